// Round 6
// baseline (192.401 us; speedup 1.0000x reference)
//
#include <hip/hip_runtime.h>

// EnhancedMoEModel: B=524288, D=32, H=64, H2=32, E=8, O=1. fp32 in/out.
// out[b] = sum_e sigmoid(relu(relu(x W1e + b1e) W2e + b2) W3e + b3) * probs[b,e]
//
// Expert-stationary MFMA: wave w owns expert w; weights live in registers as
// pre-packed fragments. Layers computed transposed (M=hidden, N=16 rows) so
// layer1's C-fragment IS layer2's B-fragment (16x16x16): no LDS round-trip.
// R5 lesson: VGPR_Count=52 proved the allocator re-loaded the 56-reg weight
// fragments from global EVERY iteration. Fix: asm-volatile pin after load
// (non-rematerializable defs) + manual x/probs prefetch pipeline.

constexpr int RB = 512;   // rows per block; 8 waves x 32 iters of 16 rows

typedef __attribute__((ext_vector_type(4))) short bf16x4;
typedef __attribute__((ext_vector_type(8))) short bf16x8;
typedef __attribute__((ext_vector_type(4))) float f32x4;

__device__ __forceinline__ short f2bf_rne(float f) {
    unsigned u = __float_as_uint(f);
    unsigned r = (u + 0x7fffu + ((u >> 16) & 1u)) >> 16;
    return (short)r;
}

// pack two fp32 -> dword of 2 bf16 (round-half-up + v_perm).
__device__ __forceinline__ unsigned pk2(float lo, float hi) {
    unsigned ulo = __float_as_uint(lo) + 0x8000u;
    unsigned uhi = __float_as_uint(hi) + 0x8000u;
    return __builtin_amdgcn_perm(uhi, ulo, 0x07060302u);
}

__device__ __forceinline__ f32x4 mfma16(bf16x4 a, bf16x4 b, f32x4 c) {
#if __has_builtin(__builtin_amdgcn_mfma_f32_16x16x16bf16_1k)
    return __builtin_amdgcn_mfma_f32_16x16x16bf16_1k(a, b, c, 0, 0, 0);
#elif __has_builtin(__builtin_amdgcn_mfma_f32_16x16x16_bf16)
    return __builtin_amdgcn_mfma_f32_16x16x16_bf16(a, b, c, 0, 0, 0);
#else
    asm volatile("v_mfma_f32_16x16x16_bf16 %0, %1, %2, %0\n\t"
                 "s_nop 7\n\ts_nop 3"
                 : "+v"(c) : "v"(a), "v"(b));
    return c;
#endif
}

// d_ws layout: w1p[8][4][64][8] bf16 @0; w2p[8][2][4][64][4] bf16 @16384sh;
// b1p[8][64][16] f32 @byte 65536; b2p[8][64][8] f32; w3p[8][64][8] f32.
__global__ void cvt_pack(const float* __restrict__ W1, const float* __restrict__ b1,
                         const float* __restrict__ W2, const float* __restrict__ b2,
                         const float* __restrict__ W3, short* __restrict__ ws) {
    int i = blockIdx.x * blockDim.x + threadIdx.x;   // 16384 threads
    short* w1p = ws;
    short* w2p = ws + 16384;
    float* b1p = (float*)(ws + 32768);
    float* b2p = b1p + 8192;
    float* w3p = b2p + 4096;
    if (i < 16384) {
        {   // w1p[e][mt][lane][j] = W1[e][d=8q+j][h=16mt+n]
            int j = i & 7, lane = (i >> 3) & 63, mt = (i >> 9) & 3, e = i >> 11;
            int n = lane & 15, q = lane >> 4;
            int d = q * 8 + j, h = 16 * mt + n;
            w1p[i] = f2bf_rne(W1[(e * 32 + d) * 64 + h]);
        }
        {   // w2p[e][mt2][kb][lane][j] = W2[e][h=16kb+4q+j][h2=16mt2+n]
            int j = i & 3, lane = (i >> 2) & 63, kb = (i >> 8) & 3,
                mt2 = (i >> 10) & 1, e = i >> 11;
            int n = lane & 15, q = lane >> 4;
            int h = 16 * kb + 4 * q + j, h2 = 16 * mt2 + n;
            w2p[i] = f2bf_rne(W2[(e * 64 + h) * 32 + h2]);
        }
    }
    if (i < 8192) {   // b1p[e][lane][mt*4+r] = b1[e][16mt+4q+r]
        int idx = i & 15, lane = (i >> 4) & 63, e = i >> 10;
        int q = lane >> 4, h = 16 * (idx >> 2) + 4 * q + (idx & 3);
        b1p[i] = b1[e * 64 + h];
    }
    if (i < 4096) {   // b2p/w3p[e][lane][mt2*4+r] = .[e][16mt2+4q+r]
        int idx = i & 7, lane = (i >> 3) & 63, e = i >> 9;
        int q = lane >> 4, h2 = 16 * (idx >> 2) + 4 * q + (idx & 3);
        b2p[i] = b2[e * 32 + h2];
        w3p[i] = W3[e * 32 + h2];
    }
}

__attribute__((amdgpu_flat_work_group_size(512, 512), amdgpu_waves_per_eu(3, 4)))
__global__ void moe_main(const float* __restrict__ x,
                         const float* __restrict__ probs,
                         const short* __restrict__ ws,
                         const float* __restrict__ b3,
                         float* __restrict__ out) {
    __shared__ float sbuf[8][RB];
    const int tid = threadIdx.x;
    const int w = tid >> 6, lane = tid & 63, n = lane & 15, q = lane >> 4;

    const short* w1p = ws;
    const short* w2p = ws + 16384;
    const float* b1p = (const float*)(ws + 32768);
    const float* b2p = b1p + 8192;
    const float* w3p = b2p + 4096;

    // Per-expert weight fragments -> registers (once per block).
    bf16x8 w1f[4];
    #pragma unroll
    for (int mt = 0; mt < 4; ++mt)
        w1f[mt] = *(const bf16x8*)(w1p + ((w * 4 + mt) * 64 + lane) * 8);
    bf16x4 w2f[2][4];
    #pragma unroll
    for (int mt2 = 0; mt2 < 2; ++mt2)
        #pragma unroll
        for (int kb = 0; kb < 4; ++kb)
            w2f[mt2][kb] = *(const bf16x4*)(w2p + (((w * 2 + mt2) * 4 + kb) * 64 + lane) * 4);
    f32x4 b1f[4];
    #pragma unroll
    for (int mt = 0; mt < 4; ++mt)
        b1f[mt] = *(const f32x4*)(b1p + (w * 64 + lane) * 16 + mt * 4);
    f32x4 b2f[2], w3f[2];
    #pragma unroll
    for (int mt2 = 0; mt2 < 2; ++mt2) {
        b2f[mt2] = *(const f32x4*)(b2p + (w * 64 + lane) * 8 + mt2 * 4);
        w3f[mt2] = *(const f32x4*)(w3p + (w * 64 + lane) * 8 + mt2 * 4);
    }
    float b3v = b3[w];

    // PIN: non-rematerializable defs -> allocator must keep fragments live
    // across the loop instead of re-loading them each iteration (R5: VGPR=52).
    asm volatile("" : "+v"(w1f[0]), "+v"(w1f[1]), "+v"(w1f[2]), "+v"(w1f[3]));
    asm volatile("" : "+v"(w2f[0][0]), "+v"(w2f[0][1]), "+v"(w2f[0][2]), "+v"(w2f[0][3]),
                      "+v"(w2f[1][0]), "+v"(w2f[1][1]), "+v"(w2f[1][2]), "+v"(w2f[1][3]));
    asm volatile("" : "+v"(b1f[0]), "+v"(b1f[1]), "+v"(b1f[2]), "+v"(b1f[3]));
    asm volatile("" : "+v"(b2f[0]), "+v"(b2f[1]), "+v"(w3f[0]), "+v"(w3f[1]), "+v"(b3v));

    const size_t rowbase = (size_t)blockIdx.x * RB;
    const float* xp = x + (rowbase + n) * 32 + q * 8;       // +512 per iter
    const float* pp = probs + (rowbase + n) * 8 + w;        // +128 per iter
    float* sb = &sbuf[w][n];                                // +16 per iter

    // Software pipeline: current tile's x/probs already in flight.
    f32x4 xa = *(const f32x4*)xp;
    f32x4 xb = *(const f32x4*)(xp + 4);
    float pb = pp[0];

    for (int it = 0; it < RB / 16; ++it) {
        // Issue next tile's loads first (clamped on last iter; 1 redundant load).
        const int adv = (it < RB / 16 - 1) ? 1 : 0;
        xp += 512 * adv; pp += 128 * adv;
        f32x4 na = *(const f32x4*)xp;
        f32x4 nb = *(const f32x4*)(xp + 4);
        float npb = pp[0];

        // Pack X^T B-fragment: lane holds x[row=n][d=8q..8q+7].
        union { bf16x8 v; unsigned u[4]; } xf;
        xf.u[0] = pk2(xa.x, xa.y); xf.u[1] = pk2(xa.z, xa.w);
        xf.u[2] = pk2(xb.x, xb.y); xf.u[3] = pk2(xb.z, xb.w);

        // Layer 1: 4x mfma 16x16x32, acc init = b1 fragment.
        f32x4 c1[4];
        #pragma unroll
        for (int mt = 0; mt < 4; ++mt)
            c1[mt] = __builtin_amdgcn_mfma_f32_16x16x32_bf16(w1f[mt], xf.v, b1f[mt], 0, 0, 0);

        // relu + pack: C1 fragment == B fragment (k=4q+r) for 16x16x16.
        bf16x4 p[4];
        #pragma unroll
        for (int mt = 0; mt < 4; ++mt) {
            union { bf16x4 v; unsigned u[2]; } t;
            t.u[0] = pk2(fmaxf(c1[mt].x, 0.f), fmaxf(c1[mt].y, 0.f));
            t.u[1] = pk2(fmaxf(c1[mt].z, 0.f), fmaxf(c1[mt].w, 0.f));
            p[mt] = t.v;
        }

        // Layer 2: 2 M-tiles x 4 K-blocks of 16x16x16, acc init = b2.
        f32x4 c2[2];
        #pragma unroll
        for (int mt2 = 0; mt2 < 2; ++mt2) {
            f32x4 a = b2f[mt2];
            #pragma unroll
            for (int kb = 0; kb < 4; ++kb)
                a = mfma16(w2f[mt2][kb], p[kb], a);
            c2[mt2] = a;
        }

        // Layer 3 + sigmoid + prob weighting; quad-reduce over q.
        float pl = 0.f;
        #pragma unroll
        for (int mt2 = 0; mt2 < 2; ++mt2) {
            pl = fmaf(fmaxf(c2[mt2].x, 0.f), w3f[mt2].x, pl);
            pl = fmaf(fmaxf(c2[mt2].y, 0.f), w3f[mt2].y, pl);
            pl = fmaf(fmaxf(c2[mt2].z, 0.f), w3f[mt2].z, pl);
            pl = fmaf(fmaxf(c2[mt2].w, 0.f), w3f[mt2].w, pl);
        }
        pl += __shfl_xor(pl, 16);
        pl += __shfl_xor(pl, 32);
        const float sig = 1.f / (1.f + __expf(-(pl + b3v)));
        if (q == 0) sb[it * 16] = sig * pb;

        xa = na; xb = nb; pb = npb;
    }

    __syncthreads();
    // Combine experts: thread t sums sbuf[0..7][t]; coalesced 2 KB store.
    float r = 0.f;
    #pragma unroll
    for (int e = 0; e < 8; ++e) r += sbuf[e][tid];
    out[rowbase + tid] = r;
}

extern "C" void kernel_launch(void* const* d_in, const int* in_sizes, int n_in,
                              void* d_out, int out_size, void* d_ws, size_t ws_size,
                              hipStream_t stream) {
    const float* x     = (const float*)d_in[0];
    const float* probs = (const float*)d_in[1];
    const float* W1    = (const float*)d_in[2];
    const float* b1    = (const float*)d_in[3];
    const float* W2    = (const float*)d_in[4];
    const float* b2    = (const float*)d_in[5];
    const float* W3    = (const float*)d_in[6];
    const float* b3    = (const float*)d_in[7];

    short* ws = (short*)d_ws;
    const int nrows = in_sizes[0] / 32;          // 524288

    hipLaunchKernelGGL(cvt_pack, dim3(64), dim3(256), 0, stream,
                       W1, b1, W2, b2, W3, ws);
    hipLaunchKernelGGL(moe_main, dim3(nrows / RB), dim3(512), 0, stream,
                       x, probs, ws, b3, (float*)d_out);
}

// Round 8
// 191.295 us; speedup vs baseline: 1.0058x; 1.0058x over previous
//
#include <hip/hip_runtime.h>

// EnhancedMoEModel: B=524288, D=32, H=64, H2=32, E=8, O=1. fp32 in/out.
// out[b] = sum_e sigmoid(relu(relu(x W1e + b1e) W2e + b2e) W3e + b3e) * probs[b,e]
//
// Expert-stationary MFMA: wave w owns expert w; packed weight fragments are
// loop-invariant (resident in unified VGPR/AGPR file — R6 proved no reloads).
// Layers transposed (M=hidden, N=16 rows): layer1 C-frag == layer2 B-frag,
// and layer3 is an MFMA with w3 replicated across rows (D[m][n]=s[n] for all
// m) -> no cross-lane shuffles anywhere in the chain.
// R7 lesson: the "w2p[16384+i]" double-offset clobbered b1p and left w2p
// poisoned -> absmax 0.898. This round reverts that single line (w2p[i]).

constexpr int RB = 512;   // rows per block; 8 waves x 32 iters of 16 rows

typedef __attribute__((ext_vector_type(4))) short bf16x4;
typedef __attribute__((ext_vector_type(8))) short bf16x8;
typedef __attribute__((ext_vector_type(4))) float f32x4;

__device__ __forceinline__ short f2bf_rne(float f) {
    unsigned u = __float_as_uint(f);
    unsigned r = (u + 0x7fffu + ((u >> 16) & 1u)) >> 16;
    return (short)r;
}

// pack two fp32 -> dword of 2 bf16 (round-half-up + v_perm, 3 VALU).
__device__ __forceinline__ unsigned pk2(float lo, float hi) {
    unsigned ulo = __float_as_uint(lo) + 0x8000u;
    unsigned uhi = __float_as_uint(hi) + 0x8000u;
    return __builtin_amdgcn_perm(uhi, ulo, 0x07060302u);
}

__device__ __forceinline__ f32x4 mfma16(bf16x4 a, bf16x4 b, f32x4 c) {
#if __has_builtin(__builtin_amdgcn_mfma_f32_16x16x16bf16_1k)
    return __builtin_amdgcn_mfma_f32_16x16x16bf16_1k(a, b, c, 0, 0, 0);
#elif __has_builtin(__builtin_amdgcn_mfma_f32_16x16x16_bf16)
    return __builtin_amdgcn_mfma_f32_16x16x16_bf16(a, b, c, 0, 0, 0);
#else
    asm volatile("v_mfma_f32_16x16x16_bf16 %0, %1, %2, %0\n\t"
                 "s_nop 7\n\ts_nop 3"
                 : "+v"(c) : "v"(a), "v"(b));
    return c;
#endif
}

// d_ws layout: w1p[8][4][64][8] bf16 @0 ; w2p[8][2][4][64][4] bf16 @16384 sh;
// b1p[8][64][16] f32 @ short-offset 32768 ; b2p[8][64][8] f32 ;
// a3p[8][2][64][4] bf16 @ short-offset 57344 (w3 replicated A-fragment).
__global__ void cvt_pack(const float* __restrict__ W1, const float* __restrict__ b1,
                         const float* __restrict__ W2, const float* __restrict__ b2,
                         const float* __restrict__ W3, short* __restrict__ ws) {
    int i = blockIdx.x * blockDim.x + threadIdx.x;   // 16384 threads
    short* w1p = ws;
    short* w2p = ws + 16384;
    float* b1p = (float*)(ws + 32768);
    float* b2p = b1p + 8192;
    short* a3p = ws + 57344;
    if (i < 16384) {
        {   // w1p[e][mt][lane][j] = W1[e][d=8q+j][h=16mt+n]  (A-frag, K=32)
            int j = i & 7, lane = (i >> 3) & 63, mt = (i >> 9) & 3, e = i >> 11;
            int n = lane & 15, q = lane >> 4;
            w1p[i] = f2bf_rne(W1[(e * 32 + q * 8 + j) * 64 + 16 * mt + n]);
        }
        {   // w2p[e][mt2][kb][lane][j] = W2[e][h=16kb+4q+j][h2=16mt2+n]
            int j = i & 3, lane = (i >> 2) & 63, kb = (i >> 8) & 3,
                mt2 = (i >> 10) & 1, e = i >> 11;
            int n = lane & 15, q = lane >> 4;
            w2p[i] = f2bf_rne(W2[(e * 64 + 16 * kb + 4 * q + j) * 32 + 16 * mt2 + n]);
        }
    }
    if (i < 8192) {   // b1p[e][lane][mt*4+r] = b1[e][16mt+4q+r]
        int idx = i & 15, lane = (i >> 4) & 63, e = i >> 10;
        int q = lane >> 4;
        b1p[i] = b1[e * 64 + 16 * (idx >> 2) + 4 * q + (idx & 3)];
    }
    if (i < 4096) {
        {   // b2p[e][lane][mt2*4+r] = b2[e][16mt2+4q+r]
            int idx = i & 7, lane = (i >> 3) & 63, e = i >> 9;
            int q = lane >> 4;
            b2p[i] = b2[e * 32 + 16 * (idx >> 2) + 4 * q + (idx & 3)];
        }
        {   // a3p[e][mt2][lane][j] = W3[e][16mt2+4q+j]  (A-frag, rows replicated)
            int j = i & 3, lane = (i >> 2) & 63, mt2 = (i >> 8) & 1, e = i >> 9;
            int q = lane >> 4;
            a3p[i] = f2bf_rne(W3[e * 32 + 16 * mt2 + 4 * q + j]);
        }
    }
}

__attribute__((amdgpu_flat_work_group_size(512, 512), amdgpu_waves_per_eu(3, 4)))
__global__ void moe_main(const float* __restrict__ x,
                         const float* __restrict__ probs,
                         const short* __restrict__ ws,
                         const float* __restrict__ b3,
                         float* __restrict__ out) {
    __shared__ float sbuf[8][RB];
    const int tid = threadIdx.x;
    const int w = tid >> 6, lane = tid & 63, n = lane & 15, q = lane >> 4;

    const short* w1p = ws;
    const short* w2p = ws + 16384;
    const float* b1p = (const float*)(ws + 32768);
    const float* b2p = b1p + 8192;
    const short* a3p = ws + 57344;

    // Loop-invariant per-expert fragments (resident across the loop).
    bf16x8 w1f[4];
    #pragma unroll
    for (int mt = 0; mt < 4; ++mt)
        w1f[mt] = *(const bf16x8*)(w1p + ((w * 4 + mt) * 64 + lane) * 8);
    bf16x4 w2f[2][4];
    #pragma unroll
    for (int mt2 = 0; mt2 < 2; ++mt2)
        #pragma unroll
        for (int kb = 0; kb < 4; ++kb)
            w2f[mt2][kb] = *(const bf16x4*)(w2p + (((w * 2 + mt2) * 4 + kb) * 64 + lane) * 4);
    f32x4 b1f[4];
    #pragma unroll
    for (int mt = 0; mt < 4; ++mt)
        b1f[mt] = *(const f32x4*)(b1p + (w * 64 + lane) * 16 + mt * 4);
    f32x4 b2f[2];
    bf16x4 a3f[2];
    #pragma unroll
    for (int mt2 = 0; mt2 < 2; ++mt2) {
        b2f[mt2] = *(const f32x4*)(b2p + (w * 64 + lane) * 8 + mt2 * 4);
        a3f[mt2] = *(const bf16x4*)(a3p + ((w * 2 + mt2) * 64 + lane) * 4);
    }
    const float b3v = b3[w];

    const size_t rowbase = (size_t)blockIdx.x * RB;
    const float* xp = x + (rowbase + n) * 32 + q * 8;       // +512 per iter
    const float* pp = probs + (rowbase + n) * 8 + w;        // +128 per iter
    float* sb = &sbuf[w][n];

    // Software pipeline: tile's x/probs in flight one iteration ahead.
    f32x4 xa = *(const f32x4*)xp;
    f32x4 xb = *(const f32x4*)(xp + 4);
    float pb = pp[0];

    for (int it = 0; it < RB / 16; ++it) {
        const int adv = (it < RB / 16 - 1) ? 1 : 0;
        xp += 512 * adv; pp += 128 * adv;
        f32x4 na = *(const f32x4*)xp;
        f32x4 nb = *(const f32x4*)(xp + 4);
        float npb = pp[0];

        // X^T B-fragment: lane holds x[row=n][d=8q..8q+7].
        union { bf16x8 v; unsigned u[4]; } xf;
        xf.u[0] = pk2(xa.x, xa.y); xf.u[1] = pk2(xa.z, xa.w);
        xf.u[2] = pk2(xb.x, xb.y); xf.u[3] = pk2(xb.z, xb.w);

        // Layer 1: 4x mfma 16x16x32, C-init = b1 fragment.
        f32x4 c1[4];
        #pragma unroll
        for (int mt = 0; mt < 4; ++mt)
            c1[mt] = __builtin_amdgcn_mfma_f32_16x16x32_bf16(w1f[mt], xf.v, b1f[mt], 0, 0, 0);

        // relu + pack: C1 fragment == B fragment (k=4q+r) for 16x16x16.
        bf16x4 p[4];
        #pragma unroll
        for (int mt = 0; mt < 4; ++mt) {
            union { bf16x4 v; unsigned u[2]; } t;
            t.u[0] = pk2(fmaxf(c1[mt].x, 0.f), fmaxf(c1[mt].y, 0.f));
            t.u[1] = pk2(fmaxf(c1[mt].z, 0.f), fmaxf(c1[mt].w, 0.f));
            p[mt] = t.v;
        }

        // Layer 2: 2 M-tiles x 4 K-blocks of 16x16x16, C-init = b2.
        f32x4 c2[2];
        #pragma unroll
        for (int mt2 = 0; mt2 < 2; ++mt2) {
            f32x4 a = b2f[mt2];
            #pragma unroll
            for (int kb = 0; kb < 4; ++kb)
                a = mfma16(w2f[mt2][kb], p[kb], a);
            c2[mt2] = a;
        }

        // relu + pack H2 -> B-fragments for the layer-3 MFMA.
        bf16x4 pc2[2];
        #pragma unroll
        for (int mt2 = 0; mt2 < 2; ++mt2) {
            union { bf16x4 v; unsigned u[2]; } t;
            t.u[0] = pk2(fmaxf(c2[mt2].x, 0.f), fmaxf(c2[mt2].y, 0.f));
            t.u[1] = pk2(fmaxf(c2[mt2].z, 0.f), fmaxf(c2[mt2].w, 0.f));
            pc2[mt2] = t.v;
        }

        // Layer 3 on the matrix pipe: A = w3 replicated over rows, so
        // D[m][n] = b3 + sum_k w3[k]*relu(H2)[k][n] = s[n] for every m.
        f32x4 b3c = {b3v, b3v, b3v, b3v};
        f32x4 sacc = mfma16(a3f[0], pc2[0], b3c);
        sacc = mfma16(a3f[1], pc2[1], sacc);

        const float sig = 1.f / (1.f + __expf(-sacc.x));
        if (q == 0) sb[it * 16] = sig * pb;

        xa = na; xb = nb; pb = npb;
    }

    __syncthreads();
    // Combine experts: thread t sums sbuf[0..7][t]; coalesced 2 KB store.
    float r = 0.f;
    #pragma unroll
    for (int e = 0; e < 8; ++e) r += sbuf[e][tid];
    out[rowbase + tid] = r;
}

extern "C" void kernel_launch(void* const* d_in, const int* in_sizes, int n_in,
                              void* d_out, int out_size, void* d_ws, size_t ws_size,
                              hipStream_t stream) {
    const float* x     = (const float*)d_in[0];
    const float* probs = (const float*)d_in[1];
    const float* W1    = (const float*)d_in[2];
    const float* b1    = (const float*)d_in[3];
    const float* W2    = (const float*)d_in[4];
    const float* b2    = (const float*)d_in[5];
    const float* W3    = (const float*)d_in[6];
    const float* b3    = (const float*)d_in[7];

    short* ws = (short*)d_ws;
    const int nrows = in_sizes[0] / 32;          // 524288

    hipLaunchKernelGGL(cvt_pack, dim3(64), dim3(256), 0, stream,
                       W1, b1, W2, b2, W3, ws);
    hipLaunchKernelGGL(moe_main, dim3(nrows / RB), dim3(512), 0, stream,
                       x, probs, ws, b3, (float*)d_out);
}